// Round 1
// baseline (821.476 us; speedup 1.0000x reference)
//
#include <hip/hip_runtime.h>
#include <hip/hip_bf16.h>
#include <math.h>

#define BM 64
#define BN 64
#define BK 16

// C[m,n] = sum_k A[m,k] * W[n,k] + bias[n]
// MODE 0: plain write to C [M,N]
// MODE 1: scatter qkv columns into q/k/v [B,H,N,dh] (B=2,H=16,N=2048,dh=64)
template <int MODE>
__global__ __launch_bounds__(256) void gemm_nt(
    const float* __restrict__ A, const float* __restrict__ W,
    const float* __restrict__ bias, float* __restrict__ C,
    float* __restrict__ q, float* __restrict__ k, float* __restrict__ v,
    int M, int N, int K)
{
    __shared__ float As[BK][BM + 1];
    __shared__ float Bs[BK][BN + 1];

    const int tid = threadIdx.x;
    const int bm = blockIdx.y * BM;
    const int bn = blockIdx.x * BN;
    const int tm = (tid & 15) * 4;   // 4 rows per thread
    const int tn = (tid >> 4) * 4;   // 4 cols per thread
    const int lr = tid >> 2;         // 0..63 tile row for loading
    const int lk = (tid & 3) * 4;    // 0,4,8,12 k offset for loading

    float acc[4][4] = {};

    for (int k0 = 0; k0 < K; k0 += BK) {
        float4 a4 = *(const float4*)&A[(size_t)(bm + lr) * K + k0 + lk];
        float4 w4 = *(const float4*)&W[(size_t)(bn + lr) * K + k0 + lk];
        As[lk + 0][lr] = a4.x; As[lk + 1][lr] = a4.y;
        As[lk + 2][lr] = a4.z; As[lk + 3][lr] = a4.w;
        Bs[lk + 0][lr] = w4.x; Bs[lk + 1][lr] = w4.y;
        Bs[lk + 2][lr] = w4.z; Bs[lk + 3][lr] = w4.w;
        __syncthreads();
#pragma unroll
        for (int kk = 0; kk < BK; kk++) {
            float av[4], wv[4];
#pragma unroll
            for (int i = 0; i < 4; i++) av[i] = As[kk][tm + i];
#pragma unroll
            for (int j = 0; j < 4; j++) wv[j] = Bs[kk][tn + j];
#pragma unroll
            for (int i = 0; i < 4; i++)
#pragma unroll
                for (int j = 0; j < 4; j++)
                    acc[i][j] = fmaf(av[i], wv[j], acc[i][j]);
        }
        __syncthreads();
    }

#pragma unroll
    for (int i = 0; i < 4; i++) {
        const int m = bm + tm + i;
#pragma unroll
        for (int j = 0; j < 4; j++) {
            const int n = bn + tn + j;
            float val = acc[i][j] + bias[n];
            if (MODE == 0) {
                C[(size_t)m * N + n] = val;
            } else {
                const int t  = n >> 10;        // 0=q 1=k 2=v
                const int d  = n & 1023;
                const int h  = d >> 6;
                const int dd = d & 63;
                const int b  = m >> 11;
                const int ii = m & 2047;
                const size_t dst = (((size_t)(b * 16 + h) * 2048) + ii) * 64 + dd;
                float* out = (t == 0) ? q : (t == 1) ? k : v;
                out[dst] = val;
            }
        }
    }
}

// in-place L2-normalize rows of 64: one wave per row; first `rows` waves -> q,
// next `rows` waves -> k
__global__ __launch_bounds__(256) void qk_norm(float* __restrict__ q,
                                               float* __restrict__ k, int rows)
{
    const int w = blockIdx.x * 4 + (threadIdx.x >> 6);
    const int lane = threadIdx.x & 63;
    float* base = (w < rows) ? q : k;
    const int r = (w < rows) ? w : (w - rows);
    float* p = base + (size_t)r * 64;
    float x = p[lane];
    float ss = x * x;
#pragma unroll
    for (int off = 32; off; off >>= 1) ss += __shfl_xor(ss, off);
    p[lane] = x / (sqrtf(ss) + 1e-6f);
}

// one wave per (b,h,i): 17-tap dilated attention, dh = 64 = wave width
__global__ __launch_bounds__(256) void attn_sparse(
    const float* __restrict__ q, const float* __restrict__ k,
    const float* __restrict__ v, float* __restrict__ o /*[B,N,D]*/)
{
    const int w = blockIdx.x * 4 + (threadIdx.x >> 6); // (b*16+h)*2048 + i
    const int lane = threadIdx.x & 63;
    const int i  = w & 2047;
    const int bh = w >> 11;        // b*16+h, 0..31

    const float* qrow  = q + (size_t)w * 64;
    const float* kbase = k + (size_t)bh * 2048 * 64;
    const float* vbase = v + (size_t)bh * 2048 * 64;

    const float qd = qrow[lane];

    float s[17];
#pragma unroll
    for (int t = 0; t < 17; t++) {
        const int j = i + 2 * t - 16;
        const bool valid = (j >= 0) && (j < 2048);
        const int jc = valid ? j : i;
        float prod = qd * kbase[(size_t)jc * 64 + lane];
#pragma unroll
        for (int off = 32; off; off >>= 1) prod += __shfl_xor(prod, off);
        s[t] = valid ? prod : -INFINITY;
    }

    float m = s[0];
#pragma unroll
    for (int t = 1; t < 17; t++) m = fmaxf(m, s[t]);
    float denom = 0.f, p[17];
#pragma unroll
    for (int t = 0; t < 17; t++) { p[t] = __expf(s[t] - m); denom += p[t]; }
    const float inv = 1.0f / denom;

    float acc = 0.f;
#pragma unroll
    for (int t = 0; t < 17; t++) {
        const int j = i + 2 * t - 16;
        if (j >= 0 && j < 2048) acc = fmaf(p[t], vbase[(size_t)j * 64 + lane], acc);
    }

    const int b = bh >> 4;
    const int h = bh & 15;
    o[((size_t)(b * 2048 + i)) * 1024 + h * 64 + lane] = acc * inv;
}

extern "C" void kernel_launch(void* const* d_in, const int* in_sizes, int n_in,
                              void* d_out, int out_size, void* d_ws, size_t ws_size,
                              hipStream_t stream)
{
    const float* x     = (const float*)d_in[0];  // [2,2048,1024]
    const float* w_qkv = (const float*)d_in[1];  // [3072,1024]
    const float* b_qkv = (const float*)d_in[2];  // [3072]
    const float* w_out = (const float*)d_in[3];  // [1024,1024]
    const float* b_out = (const float*)d_in[4];  // [1024]
    float* out = (float*)d_out;                  // [2,2048,1024]

    const int Bn = 2, Nn = 2048, Dn = 1024;
    const int M = Bn * Nn;          // 4096
    const int rows = 2 * 16 * 2048; // per-tensor q/k rows = 65536

    float* q  = (float*)d_ws;                    // [2,16,2048,64] = 4M floats
    float* kk = q + (size_t)rows * 64;
    float* vv = kk + (size_t)rows * 64;
    float* ao = vv + (size_t)rows * 64;          // [2,2048,1024]

    // 1) qkv projection, scatter into q/k/v head layout
    {
        dim3 grid(3 * Dn / BN, M / BM);
        hipLaunchKernelGGL((gemm_nt<1>), grid, dim3(256), 0, stream,
                           x, w_qkv, b_qkv, nullptr, q, kk, vv, M, 3 * Dn, Dn);
    }
    // 2) qk-norm (q rows then k rows)
    {
        const int waves = 2 * rows;
        hipLaunchKernelGGL(qk_norm, dim3(waves / 4), dim3(256), 0, stream,
                           q, kk, rows);
    }
    // 3) sparse dilated attention
    {
        hipLaunchKernelGGL(attn_sparse, dim3(rows / 4), dim3(256), 0, stream,
                           q, kk, vv, ao);
    }
    // 4) output projection
    {
        dim3 grid(Dn / BN, M / BM);
        hipLaunchKernelGGL((gemm_nt<0>), grid, dim3(256), 0, stream,
                           ao, w_out, b_out, out, nullptr, nullptr, nullptr,
                           M, Dn, Dn);
    }
}

// Round 2
// 340.907 us; speedup vs baseline: 2.4097x; 2.4097x over previous
//
#include <hip/hip_runtime.h>
#include <hip/hip_bf16.h>
#include <math.h>

typedef __bf16 bf16x8 __attribute__((ext_vector_type(8)));
typedef float f32x4 __attribute__((ext_vector_type(4)));

#define TM 128
#define TN 128
#define TK 32

// Split one fp32 into hi/lo bf16 pair: x ~= hi + lo, |lo| <= 2^-8 |x|.
__device__ inline void split8(const float* __restrict__ s, bf16x8& h, bf16x8& l) {
#pragma unroll
    for (int j = 0; j < 8; j++) {
        float x = s[j];
        __bf16 hb = (__bf16)x;
        h[j] = hb;
        l[j] = (__bf16)(x - (float)hb);
    }
}

// C[m,n] = sum_k A[m,k]*W[n,k] + bias[n], via 3-term split-bf16 MFMA.
// MODE 0: plain write to C [M,N]
// MODE 1: scatter qkv columns into q/k/v [B,H,N,dh] (B=2,H=16,N=2048,dh=64)
template <int MODE>
__global__ __launch_bounds__(256) void gemm_mfma(
    const float* __restrict__ A, const float* __restrict__ W,
    const float* __restrict__ bias, float* __restrict__ C,
    float* __restrict__ q, float* __restrict__ k, float* __restrict__ v,
    int M, int N, int K)
{
    __shared__ __bf16 Ah[TM][TK];
    __shared__ __bf16 Al[TM][TK];
    __shared__ __bf16 Wh[TN][TK];
    __shared__ __bf16 Wl[TN][TK];

    const int tid  = threadIdx.x;
    const int lane = tid & 63;
    const int wave = tid >> 6;
    const int bm = blockIdx.y * TM;
    const int bn = blockIdx.x * TN;
    const int wm = (wave >> 1) * 64;   // wave's 64x64 quadrant
    const int wn = (wave & 1) * 64;

    const int srow  = tid >> 1;          // 0..127 staging row
    const int skoff = (tid & 1) * 16;    // 0 or 16

    const int frow = lane & 15;          // fragment row/col within 16-tile
    const int fk   = (lane >> 4) * 8;    // fragment k offset

    f32x4 acc[4][4] = {};

    for (int k0 = 0; k0 < K; k0 += TK) {
        // ---- stage A tile (fp32 -> hi/lo bf16) ----
        {
            const float* src = &A[(size_t)(bm + srow) * K + k0 + skoff];
            float buf[16];
            *(float4*)&buf[0]  = ((const float4*)src)[0];
            *(float4*)&buf[4]  = ((const float4*)src)[1];
            *(float4*)&buf[8]  = ((const float4*)src)[2];
            *(float4*)&buf[12] = ((const float4*)src)[3];
            bf16x8 h0, l0, h1, l1;
            split8(&buf[0], h0, l0);
            split8(&buf[8], h1, l1);
            *(bf16x8*)&Ah[srow][skoff]     = h0;
            *(bf16x8*)&Ah[srow][skoff + 8] = h1;
            *(bf16x8*)&Al[srow][skoff]     = l0;
            *(bf16x8*)&Al[srow][skoff + 8] = l1;
        }
        // ---- stage W tile ----
        {
            const float* src = &W[(size_t)(bn + srow) * K + k0 + skoff];
            float buf[16];
            *(float4*)&buf[0]  = ((const float4*)src)[0];
            *(float4*)&buf[4]  = ((const float4*)src)[1];
            *(float4*)&buf[8]  = ((const float4*)src)[2];
            *(float4*)&buf[12] = ((const float4*)src)[3];
            bf16x8 h0, l0, h1, l1;
            split8(&buf[0], h0, l0);
            split8(&buf[8], h1, l1);
            *(bf16x8*)&Wh[srow][skoff]     = h0;
            *(bf16x8*)&Wh[srow][skoff + 8] = h1;
            *(bf16x8*)&Wl[srow][skoff]     = l0;
            *(bf16x8*)&Wl[srow][skoff + 8] = l1;
        }
        __syncthreads();

        bf16x8 aH[4], aL[4], bH[4], bL[4];
#pragma unroll
        for (int t = 0; t < 4; t++) {
            aH[t] = *(const bf16x8*)&Ah[wm + t * 16 + frow][fk];
            aL[t] = *(const bf16x8*)&Al[wm + t * 16 + frow][fk];
            bH[t] = *(const bf16x8*)&Wh[wn + t * 16 + frow][fk];
            bL[t] = *(const bf16x8*)&Wl[wn + t * 16 + frow][fk];
        }
#pragma unroll
        for (int i = 0; i < 4; i++)
#pragma unroll
            for (int j = 0; j < 4; j++) {
                acc[i][j] = __builtin_amdgcn_mfma_f32_16x16x32_bf16(aH[i], bH[j], acc[i][j], 0, 0, 0);
                acc[i][j] = __builtin_amdgcn_mfma_f32_16x16x32_bf16(aH[i], bL[j], acc[i][j], 0, 0, 0);
                acc[i][j] = __builtin_amdgcn_mfma_f32_16x16x32_bf16(aL[i], bH[j], acc[i][j], 0, 0, 0);
            }
        __syncthreads();
    }

    // ---- epilogue: C/D layout col=lane&15, row=(lane>>4)*4+reg ----
#pragma unroll
    for (int i = 0; i < 4; i++) {
        const int gmBase = bm + wm + i * 16 + (lane >> 4) * 4;
#pragma unroll
        for (int j = 0; j < 4; j++) {
            const int gn = bn + wn + j * 16 + (lane & 15);
            const float bv = bias[gn];
#pragma unroll
            for (int r = 0; r < 4; r++) {
                const int gm = gmBase + r;
                const float val = acc[i][j][r] + bv;
                if (MODE == 0) {
                    C[(size_t)gm * N + gn] = val;
                } else {
                    const int t  = gn >> 10;       // 0=q 1=k 2=v
                    const int d  = gn & 1023;
                    const int h  = d >> 6;
                    const int dd = d & 63;
                    const int b  = gm >> 11;
                    const int ii = gm & 2047;
                    const size_t dst = (((size_t)(b * 16 + h) * 2048) + ii) * 64 + dd;
                    float* outp = (t == 0) ? q : (t == 1) ? k : v;
                    outp[dst] = val;
                }
            }
        }
    }
}

// in-place L2-normalize rows of 64: one wave per row
__global__ __launch_bounds__(256) void qk_norm(float* __restrict__ q,
                                               float* __restrict__ k, int rows)
{
    const int w = blockIdx.x * 4 + (threadIdx.x >> 6);
    const int lane = threadIdx.x & 63;
    float* base = (w < rows) ? q : k;
    const int r = (w < rows) ? w : (w - rows);
    float* p = base + (size_t)r * 64;
    float x = p[lane];
    float ss = x * x;
#pragma unroll
    for (int off = 32; off; off >>= 1) ss += __shfl_xor(ss, off);
    p[lane] = x / (sqrtf(ss) + 1e-6f);
}

// one wave per (b,h,i): 17-tap dilated attention, dh = 64 = wave width
__global__ __launch_bounds__(256) void attn_sparse(
    const float* __restrict__ q, const float* __restrict__ k,
    const float* __restrict__ v, float* __restrict__ o /*[B,N,D]*/)
{
    const int w = blockIdx.x * 4 + (threadIdx.x >> 6); // (b*16+h)*2048 + i
    const int lane = threadIdx.x & 63;
    const int i  = w & 2047;
    const int bh = w >> 11;        // b*16+h, 0..31

    const float* qrow  = q + (size_t)w * 64;
    const float* kbase = k + (size_t)bh * 2048 * 64;
    const float* vbase = v + (size_t)bh * 2048 * 64;

    const float qd = qrow[lane];

    float s[17];
#pragma unroll
    for (int t = 0; t < 17; t++) {
        const int j = i + 2 * t - 16;
        const bool valid = (j >= 0) && (j < 2048);
        const int jc = valid ? j : i;
        float prod = qd * kbase[(size_t)jc * 64 + lane];
#pragma unroll
        for (int off = 32; off; off >>= 1) prod += __shfl_xor(prod, off);
        s[t] = valid ? prod : -INFINITY;
    }

    float m = s[0];
#pragma unroll
    for (int t = 1; t < 17; t++) m = fmaxf(m, s[t]);
    float denom = 0.f, p[17];
#pragma unroll
    for (int t = 0; t < 17; t++) { p[t] = __expf(s[t] - m); denom += p[t]; }
    const float inv = 1.0f / denom;

    float acc = 0.f;
#pragma unroll
    for (int t = 0; t < 17; t++) {
        const int j = i + 2 * t - 16;
        if (j >= 0 && j < 2048) acc = fmaf(p[t], vbase[(size_t)j * 64 + lane], acc);
    }

    const int b = bh >> 4;
    const int h = bh & 15;
    o[((size_t)(b * 2048 + i)) * 1024 + h * 64 + lane] = acc * inv;
}

extern "C" void kernel_launch(void* const* d_in, const int* in_sizes, int n_in,
                              void* d_out, int out_size, void* d_ws, size_t ws_size,
                              hipStream_t stream)
{
    const float* x     = (const float*)d_in[0];  // [2,2048,1024]
    const float* w_qkv = (const float*)d_in[1];  // [3072,1024]
    const float* b_qkv = (const float*)d_in[2];  // [3072]
    const float* w_out = (const float*)d_in[3];  // [1024,1024]
    const float* b_out = (const float*)d_in[4];  // [1024]
    float* out = (float*)d_out;                  // [2,2048,1024]

    const int Bn = 2, Nn = 2048, Dn = 1024;
    const int M = Bn * Nn;          // 4096
    const int rows = 2 * 16 * 2048; // per-tensor q/k rows = 65536

    float* q  = (float*)d_ws;                    // [2,16,2048,64]
    float* kk = q + (size_t)rows * 64;
    float* vv = kk + (size_t)rows * 64;
    float* ao = vv + (size_t)rows * 64;          // [2,2048,1024]

    // 1) qkv projection (split-bf16 MFMA), scatter into q/k/v head layout
    {
        dim3 grid(3 * Dn / TN, M / TM);
        hipLaunchKernelGGL((gemm_mfma<1>), grid, dim3(256), 0, stream,
                           x, w_qkv, b_qkv, nullptr, q, kk, vv, M, 3 * Dn, Dn);
    }
    // 2) qk-norm
    {
        const int waves = 2 * rows;
        hipLaunchKernelGGL(qk_norm, dim3(waves / 4), dim3(256), 0, stream,
                           q, kk, rows);
    }
    // 3) sparse dilated attention
    {
        hipLaunchKernelGGL(attn_sparse, dim3(rows / 4), dim3(256), 0, stream,
                           q, kk, vv, ao);
    }
    // 4) output projection (split-bf16 MFMA)
    {
        dim3 grid(Dn / TN, M / TM);
        hipLaunchKernelGGL((gemm_mfma<0>), grid, dim3(256), 0, stream,
                           ao, w_out, b_out, out, nullptr, nullptr, nullptr,
                           M, Dn, Dn);
    }
}

// Round 3
// 335.912 us; speedup vs baseline: 2.4455x; 1.0149x over previous
//
#include <hip/hip_runtime.h>
#include <hip/hip_bf16.h>
#include <math.h>

typedef __bf16 bf16x8 __attribute__((ext_vector_type(8)));
typedef float f32x4 __attribute__((ext_vector_type(4)));

#define TM 128
#define TN 128
#define BK 32  // bf16 elements per K-tile

__device__ inline void async16(const void* g, void* l) {
    __builtin_amdgcn_global_load_lds(
        (const __attribute__((address_space(1))) unsigned int*)g,
        (__attribute__((address_space(3))) unsigned int*)l, 16, 0, 0);
}

// Split fp32 arrays into hi/lo bf16 pairs. blockIdx.y selects array {x, w_qkv, w_out}.
__global__ __launch_bounds__(256) void split_mat(
    const float* __restrict__ s0, __bf16* __restrict__ h0, __bf16* __restrict__ l0, int n0,
    const float* __restrict__ s1, __bf16* __restrict__ h1, __bf16* __restrict__ l1, int n1,
    const float* __restrict__ s2, __bf16* __restrict__ h2, __bf16* __restrict__ l2, int n2)
{
    const float* s; __bf16* h; __bf16* l; int n;
    if (blockIdx.y == 0)      { s = s0; h = h0; l = l0; n = n0; }
    else if (blockIdx.y == 1) { s = s1; h = h1; l = l1; n = n1; }
    else                      { s = s2; h = h2; l = l2; n = n2; }
    const int base = (blockIdx.x * 256 + threadIdx.x) * 8;
    if (base >= n) return;
    float4 a = ((const float4*)(s + base))[0];
    float4 b = ((const float4*)(s + base))[1];
    float buf[8] = {a.x, a.y, a.z, a.w, b.x, b.y, b.z, b.w};
    bf16x8 hv, lv;
#pragma unroll
    for (int j = 0; j < 8; j++) {
        __bf16 hb = (__bf16)buf[j];
        hv[j] = hb;
        lv[j] = (__bf16)(buf[j] - (float)hb);
    }
    *(bf16x8*)(h + base) = hv;
    *(bf16x8*)(l + base) = lv;
}

// C[m,n] = sum_k (Ah+Al)[m,k]*(Wh+Wl)[n,k] + bias[n]  (3-term MFMA, al*wl dropped)
// MODE 0: fp32 C [M,N]
// MODE 1: scatter to q/k bf16 and v split (vh,vl), layout [B,H,N,64]
template <int MODE>
__global__ __launch_bounds__(256) void gemm_split(
    const __bf16* __restrict__ Ah, const __bf16* __restrict__ Al,
    const __bf16* __restrict__ Wh, const __bf16* __restrict__ Wl,
    const float* __restrict__ bias, float* __restrict__ C,
    __bf16* __restrict__ q, __bf16* __restrict__ k,
    __bf16* __restrict__ vh, __bf16* __restrict__ vl,
    int M, int N, int K)
{
    __shared__ __bf16 sAh[TM][BK];
    __shared__ __bf16 sAl[TM][BK];
    __shared__ __bf16 sWh[TN][BK];
    __shared__ __bf16 sWl[TN][BK];

    const int tid  = threadIdx.x;
    const int lane = tid & 63;
    const int wave = tid >> 6;
    const int bm = blockIdx.y * TM;
    const int bn = blockIdx.x * TN;
    const int wm = (wave >> 1) * 64;
    const int wn = (wave & 1) * 64;
    const int frow = lane & 15;
    const int fk   = (lane >> 4) * 8;

    // staging chunks: 512 x 16B per tile; thread handles chunks tid and tid+256
    const int c0 = tid, c1 = tid + 256;
    const int r0 = c0 >> 2, b0 = (c0 & 3) * 16;
    const int r1 = c1 >> 2, b1 = (c1 & 3) * 16;

    f32x4 acc[4][4] = {};

    for (int k0 = 0; k0 < K; k0 += BK) {
#define STAGE(S, G, ROW0)                                                     \
        do {                                                                  \
            const char* g0 = (const char*)(G) +                               \
                ((size_t)((ROW0) + r0) * K + k0) * 2 + b0;                    \
            const char* g1 = (const char*)(G) +                               \
                ((size_t)((ROW0) + r1) * K + k0) * 2 + b1;                    \
            async16(g0, (char*)&S[0][0] + c0 * 16);                           \
            async16(g1, (char*)&S[0][0] + c1 * 16);                           \
        } while (0)
        STAGE(sAh, Ah, bm);
        STAGE(sAl, Al, bm);
        STAGE(sWh, Wh, bn);
        STAGE(sWl, Wl, bn);
#undef STAGE
        __syncthreads();

        bf16x8 aH[4], aL[4], bH[4], bL[4];
#pragma unroll
        for (int t = 0; t < 4; t++) {
            aH[t] = *(const bf16x8*)&sAh[wm + t * 16 + frow][fk];
            aL[t] = *(const bf16x8*)&sAl[wm + t * 16 + frow][fk];
            bH[t] = *(const bf16x8*)&sWh[wn + t * 16 + frow][fk];
            bL[t] = *(const bf16x8*)&sWl[wn + t * 16 + frow][fk];
        }
#pragma unroll
        for (int i = 0; i < 4; i++)
#pragma unroll
            for (int j = 0; j < 4; j++) {
                acc[i][j] = __builtin_amdgcn_mfma_f32_16x16x32_bf16(aH[i], bH[j], acc[i][j], 0, 0, 0);
                acc[i][j] = __builtin_amdgcn_mfma_f32_16x16x32_bf16(aH[i], bL[j], acc[i][j], 0, 0, 0);
                acc[i][j] = __builtin_amdgcn_mfma_f32_16x16x32_bf16(aL[i], bH[j], acc[i][j], 0, 0, 0);
            }
        __syncthreads();
    }

    // epilogue: C/D layout col=lane&15, row=(lane>>4)*4+reg
#pragma unroll
    for (int i = 0; i < 4; i++) {
        const int gmBase = bm + wm + i * 16 + (lane >> 4) * 4;
#pragma unroll
        for (int j = 0; j < 4; j++) {
            const int gn = bn + wn + j * 16 + (lane & 15);
            const float bv = bias[gn];
#pragma unroll
            for (int r = 0; r < 4; r++) {
                const int gm = gmBase + r;
                const float val = acc[i][j][r] + bv;
                if (MODE == 0) {
                    C[(size_t)gm * N + gn] = val;
                } else {
                    const int t  = gn >> 10;       // 0=q 1=k 2=v
                    const int d  = gn & 1023;
                    const int h  = d >> 6;
                    const int dd = d & 63;
                    const int b  = gm >> 11;
                    const int ii = gm & 2047;
                    const size_t dst = (((size_t)(b * 16 + h) * 2048) + ii) * 64 + dd;
                    if (t == 0)      q[dst] = (__bf16)val;
                    else if (t == 1) k[dst] = (__bf16)val;
                    else {
                        __bf16 hv = (__bf16)val;
                        vh[dst] = hv;
                        vl[dst] = (__bf16)(val - (float)hv);
                    }
                }
            }
        }
    }
}

// in-place L2-normalize bf16 rows of 64: one wave per row
__global__ __launch_bounds__(256) void qk_norm(__bf16* __restrict__ q,
                                               __bf16* __restrict__ k, int rows)
{
    const int w = blockIdx.x * 4 + (threadIdx.x >> 6);
    const int lane = threadIdx.x & 63;
    __bf16* base = (w < rows) ? q : k;
    const int r = (w < rows) ? w : (w - rows);
    __bf16* p = base + (size_t)r * 64;
    float x = (float)p[lane];
    float ss = x * x;
#pragma unroll
    for (int off = 32; off; off >>= 1) ss += __shfl_xor(ss, off);
    p[lane] = (__bf16)(x / (sqrtf(ss) + 1e-6f));
}

// one wave per (b,h,i): 17-tap dilated attention; writes split-bf16 output
__global__ __launch_bounds__(256) void attn_sparse(
    const __bf16* __restrict__ q, const __bf16* __restrict__ k,
    const __bf16* __restrict__ vh, const __bf16* __restrict__ vl,
    __bf16* __restrict__ oh, __bf16* __restrict__ ol /*[B,N,D]*/)
{
    const int w = blockIdx.x * 4 + (threadIdx.x >> 6); // (b*16+h)*2048 + i
    const int lane = threadIdx.x & 63;
    const int i  = w & 2047;
    const int bh = w >> 11;

    const __bf16* qrow  = q  + (size_t)w * 64;
    const __bf16* kbase = k  + (size_t)bh * 2048 * 64;
    const __bf16* vhb   = vh + (size_t)bh * 2048 * 64;
    const __bf16* vlb   = vl + (size_t)bh * 2048 * 64;

    const float qd = (float)qrow[lane];

    float s[17];
#pragma unroll
    for (int t = 0; t < 17; t++) {
        const int j = i + 2 * t - 16;
        const bool valid = (j >= 0) && (j < 2048);
        const int jc = valid ? j : i;
        float prod = qd * (float)kbase[(size_t)jc * 64 + lane];
#pragma unroll
        for (int off = 32; off; off >>= 1) prod += __shfl_xor(prod, off);
        s[t] = valid ? prod : -INFINITY;
    }

    float m = s[0];
#pragma unroll
    for (int t = 1; t < 17; t++) m = fmaxf(m, s[t]);
    float denom = 0.f, p[17];
#pragma unroll
    for (int t = 0; t < 17; t++) { p[t] = __expf(s[t] - m); denom += p[t]; }
    const float inv = 1.0f / denom;

    float acc = 0.f;
#pragma unroll
    for (int t = 0; t < 17; t++) {
        const int j = i + 2 * t - 16;
        if (j >= 0 && j < 2048) {
            const size_t off = (size_t)j * 64 + lane;
            acc = fmaf(p[t], (float)vhb[off] + (float)vlb[off], acc);
        }
    }

    const int b = bh >> 4;
    const int h = bh & 15;
    const float r = acc * inv;
    const size_t idx = ((size_t)(b * 2048 + i)) * 1024 + h * 64 + lane;
    __bf16 hr = (__bf16)r;
    oh[idx] = hr;
    ol[idx] = (__bf16)(r - (float)hr);
}

extern "C" void kernel_launch(void* const* d_in, const int* in_sizes, int n_in,
                              void* d_out, int out_size, void* d_ws, size_t ws_size,
                              hipStream_t stream)
{
    const float* x     = (const float*)d_in[0];  // [2,2048,1024]
    const float* w_qkv = (const float*)d_in[1];  // [3072,1024]
    const float* b_qkv = (const float*)d_in[2];  // [3072]
    const float* w_out = (const float*)d_in[3];  // [1024,1024]
    const float* b_out = (const float*)d_in[4];  // [1024]
    float* out = (float*)d_out;                  // [2,2048,1024]

    const int Dn = 1024;
    const int M  = 4096;                 // B*N
    const int rows = 65536;              // B*H*N q-rows
    const int nx = 4194304, nwq = 3145728, nwo = 1048576;

    char* p = (char*)d_ws;
    __bf16* q   = (__bf16*)p;                 p += (size_t)nx * 2;  // 8 MiB
    __bf16* kk  = (__bf16*)p;                 p += (size_t)nx * 2;
    __bf16* vvh = (__bf16*)p;                 p += (size_t)nx * 2;
    __bf16* vvl = (__bf16*)p;                 p += (size_t)nx * 2;
    __bf16* xh  = (__bf16*)p;                 p += (size_t)nx * 2;  // -> aoh after gemm1
    __bf16* xl  = (__bf16*)p;                 p += (size_t)nx * 2;  // -> aol
    __bf16* wqh = (__bf16*)p;                 p += (size_t)nwq * 2;
    __bf16* wql = (__bf16*)p;                 p += (size_t)nwq * 2;
    __bf16* woh = (__bf16*)p;                 p += (size_t)nwo * 2;
    __bf16* wol = (__bf16*)p;                 p += (size_t)nwo * 2;
    __bf16* aoh = xh;
    __bf16* aol = xl;

    // 0) split fp32 -> hi/lo bf16 for x, w_qkv, w_out
    {
        dim3 grid(nx / 8 / 256, 3);
        hipLaunchKernelGGL(split_mat, grid, dim3(256), 0, stream,
                           x, xh, xl, nx,
                           w_qkv, wqh, wql, nwq,
                           w_out, woh, wol, nwo);
    }
    // 1) qkv projection -> q,k bf16 + v split, head layout
    {
        dim3 grid(3 * Dn / TN, M / TM);
        hipLaunchKernelGGL((gemm_split<1>), grid, dim3(256), 0, stream,
                           xh, xl, wqh, wql, b_qkv, nullptr,
                           q, kk, vvh, vvl, M, 3 * Dn, Dn);
    }
    // 2) qk-norm
    hipLaunchKernelGGL(qk_norm, dim3(2 * rows / 4), dim3(256), 0, stream,
                       q, kk, rows);
    // 3) sparse dilated attention -> split-bf16 ao
    hipLaunchKernelGGL(attn_sparse, dim3(rows / 4), dim3(256), 0, stream,
                       q, kk, vvh, vvl, aoh, aol);
    // 4) output projection -> fp32 out
    {
        dim3 grid(Dn / TN, M / TM);
        hipLaunchKernelGGL((gemm_split<0>), grid, dim3(256), 0, stream,
                           aoh, aol, woh, wol, b_out, out,
                           nullptr, nullptr, nullptr, nullptr, M, Dn, Dn);
    }
}

// Round 4
// 240.794 us; speedup vs baseline: 3.4115x; 1.3950x over previous
//
#include <hip/hip_runtime.h>
#include <hip/hip_bf16.h>
#include <math.h>

typedef __bf16 bf16x8 __attribute__((ext_vector_type(8)));
typedef __bf16 bf16x4 __attribute__((ext_vector_type(4)));
typedef float f32x4 __attribute__((ext_vector_type(4)));

#define TM 128
#define TN 128
#define BK 32  // bf16 elements per K-tile

__device__ inline void async16(const void* g, void* l) {
    __builtin_amdgcn_global_load_lds(
        (const __attribute__((address_space(1))) unsigned int*)g,
        (__attribute__((address_space(3))) unsigned int*)l, 16, 0, 0);
}

// Split fp32 arrays into hi/lo bf16 pairs. blockIdx.y selects array {x, w_qkv, w_out}.
__global__ __launch_bounds__(256) void split_mat(
    const float* __restrict__ s0, __bf16* __restrict__ h0, __bf16* __restrict__ l0, int n0,
    const float* __restrict__ s1, __bf16* __restrict__ h1, __bf16* __restrict__ l1, int n1,
    const float* __restrict__ s2, __bf16* __restrict__ h2, __bf16* __restrict__ l2, int n2)
{
    const float* s; __bf16* h; __bf16* l; int n;
    if (blockIdx.y == 0)      { s = s0; h = h0; l = l0; n = n0; }
    else if (blockIdx.y == 1) { s = s1; h = h1; l = l1; n = n1; }
    else                      { s = s2; h = h2; l = l2; n = n2; }
    const int base = (blockIdx.x * 256 + threadIdx.x) * 8;
    if (base >= n) return;
    float4 a = ((const float4*)(s + base))[0];
    float4 b = ((const float4*)(s + base))[1];
    float buf[8] = {a.x, a.y, a.z, a.w, b.x, b.y, b.z, b.w};
    bf16x8 hv, lv;
#pragma unroll
    for (int j = 0; j < 8; j++) {
        __bf16 hb = (__bf16)buf[j];
        hv[j] = hb;
        lv[j] = (__bf16)(buf[j] - (float)hb);
    }
    *(bf16x8*)(h + base) = hv;
    *(bf16x8*)(l + base) = lv;
}

// QKV projection: C = (Ah+Al)(Wh+Wl)^T + bias (3-term MFMA), fused QK-norm,
// scatter q/k (normalized) and v as bf16 into [B,H,N,64].
__global__ __launch_bounds__(256) void gemm_qkv(
    const __bf16* __restrict__ Ah, const __bf16* __restrict__ Al,
    const __bf16* __restrict__ Wh, const __bf16* __restrict__ Wl,
    const float* __restrict__ bias,
    __bf16* __restrict__ q, __bf16* __restrict__ k, __bf16* __restrict__ v,
    int M, int N, int K)
{
    __shared__ __bf16 sAh[TM][BK];
    __shared__ __bf16 sAl[TM][BK];
    __shared__ __bf16 sWh[TN][BK];
    __shared__ __bf16 sWl[TN][BK];

    const int tid  = threadIdx.x;
    const int lane = tid & 63;
    const int wave = tid >> 6;
    const int bm = blockIdx.y * TM;
    const int bn = blockIdx.x * TN;
    const int wm = (wave >> 1) * 64;
    const int wn = (wave & 1) * 64;
    const int frow = lane & 15;
    const int fk   = (lane >> 4) * 8;

    const int c0 = tid, c1 = tid + 256;
    const int r0 = c0 >> 2, b0 = (c0 & 3) * 16;
    const int r1 = c1 >> 2, b1 = (c1 & 3) * 16;

    f32x4 acc[4][4] = {};

    for (int k0 = 0; k0 < K; k0 += BK) {
#define STAGE(S, G, ROW0)                                                     \
        do {                                                                  \
            const char* g0 = (const char*)(G) +                               \
                ((size_t)((ROW0) + r0) * K + k0) * 2 + b0;                    \
            const char* g1 = (const char*)(G) +                               \
                ((size_t)((ROW0) + r1) * K + k0) * 2 + b1;                    \
            async16(g0, (char*)&S[0][0] + c0 * 16);                           \
            async16(g1, (char*)&S[0][0] + c1 * 16);                           \
        } while (0)
        STAGE(sAh, Ah, bm);
        STAGE(sAl, Al, bm);
        STAGE(sWh, Wh, bn);
        STAGE(sWl, Wl, bn);
        __syncthreads();

        bf16x8 aH[4], aL[4], bH[4], bL[4];
#pragma unroll
        for (int t = 0; t < 4; t++) {
            aH[t] = *(const bf16x8*)&sAh[wm + t * 16 + frow][fk];
            aL[t] = *(const bf16x8*)&sAl[wm + t * 16 + frow][fk];
            bH[t] = *(const bf16x8*)&sWh[wn + t * 16 + frow][fk];
            bL[t] = *(const bf16x8*)&sWl[wn + t * 16 + frow][fk];
        }
#pragma unroll
        for (int i = 0; i < 4; i++)
#pragma unroll
            for (int j = 0; j < 4; j++) {
                acc[i][j] = __builtin_amdgcn_mfma_f32_16x16x32_bf16(aH[i], bH[j], acc[i][j], 0, 0, 0);
                acc[i][j] = __builtin_amdgcn_mfma_f32_16x16x32_bf16(aH[i], bL[j], acc[i][j], 0, 0, 0);
                acc[i][j] = __builtin_amdgcn_mfma_f32_16x16x32_bf16(aL[i], bH[j], acc[i][j], 0, 0, 0);
            }
        __syncthreads();
    }

    // wave's 64-col window = exactly one (tensor t, head h)
    const int col0 = bn + wn;
    const int t  = col0 >> 10;            // 0=q 1=k 2=v
    const int h  = (col0 & 1023) >> 6;

    float bv[4];
#pragma unroll
    for (int j = 0; j < 4; j++) bv[j] = bias[col0 + j * 16 + (lane & 15)];

    // fused QK-norm: per output row, 1/(||row||+eps); row spread over j regs x 16 lanes
    float inv_n[4][4];
    if (t < 2) {
#pragma unroll
        for (int i = 0; i < 4; i++)
#pragma unroll
            for (int r = 0; r < 4; r++) {
                float ss = 0.f;
#pragma unroll
                for (int j = 0; j < 4; j++) {
                    float val = acc[i][j][r] + bv[j];
                    ss = fmaf(val, val, ss);
                }
                ss += __shfl_xor(ss, 1);
                ss += __shfl_xor(ss, 2);
                ss += __shfl_xor(ss, 4);
                ss += __shfl_xor(ss, 8);
                inv_n[i][r] = 1.0f / (sqrtf(ss) + 1e-6f);
            }
    }

    __bf16* dstbase = (t == 0) ? q : (t == 1) ? k : v;
#pragma unroll
    for (int i = 0; i < 4; i++) {
        const int gmBase = bm + wm + i * 16 + (lane >> 4) * 4;
#pragma unroll
        for (int j = 0; j < 4; j++) {
            const int dd = (wn & 63) + j * 16 + (lane & 15); // 0..63 within head
#pragma unroll
            for (int r = 0; r < 4; r++) {
                const int gm = gmBase + r;
                float val = acc[i][j][r] + bv[j];
                if (t < 2) val *= inv_n[i][r];
                const int b  = gm >> 11;
                const int ii = gm & 2047;
                const size_t dst = (((size_t)(b * 16 + h) * 2048) + ii) * 64 + dd;
                dstbase[dst] = (__bf16)val;
            }
        }
    }
}

// Out projection: C = A(Wh+Wl)^T + bias, A plain bf16 (2-term MFMA), fp32 out.
__global__ __launch_bounds__(256) void gemm_out(
    const __bf16* __restrict__ A,
    const __bf16* __restrict__ Wh, const __bf16* __restrict__ Wl,
    const float* __restrict__ bias, float* __restrict__ C,
    int M, int N, int K)
{
    __shared__ __bf16 sA[TM][BK];
    __shared__ __bf16 sWh[TN][BK];
    __shared__ __bf16 sWl[TN][BK];

    const int tid  = threadIdx.x;
    const int lane = tid & 63;
    const int wave = tid >> 6;
    const int bm = blockIdx.y * TM;
    const int bn = blockIdx.x * TN;
    const int wm = (wave >> 1) * 64;
    const int wn = (wave & 1) * 64;
    const int frow = lane & 15;
    const int fk   = (lane >> 4) * 8;

    const int c0 = tid, c1 = tid + 256;
    const int r0 = c0 >> 2, b0 = (c0 & 3) * 16;
    const int r1 = c1 >> 2, b1 = (c1 & 3) * 16;

    f32x4 acc[4][4] = {};

    for (int k0 = 0; k0 < K; k0 += BK) {
        STAGE(sA,  A,  bm);
        STAGE(sWh, Wh, bn);
        STAGE(sWl, Wl, bn);
#undef STAGE
        __syncthreads();

        bf16x8 aH[4], bH[4], bL[4];
#pragma unroll
        for (int t = 0; t < 4; t++) {
            aH[t] = *(const bf16x8*)&sA[wm + t * 16 + frow][fk];
            bH[t] = *(const bf16x8*)&sWh[wn + t * 16 + frow][fk];
            bL[t] = *(const bf16x8*)&sWl[wn + t * 16 + frow][fk];
        }
#pragma unroll
        for (int i = 0; i < 4; i++)
#pragma unroll
            for (int j = 0; j < 4; j++) {
                acc[i][j] = __builtin_amdgcn_mfma_f32_16x16x32_bf16(aH[i], bH[j], acc[i][j], 0, 0, 0);
                acc[i][j] = __builtin_amdgcn_mfma_f32_16x16x32_bf16(aH[i], bL[j], acc[i][j], 0, 0, 0);
            }
        __syncthreads();
    }

#pragma unroll
    for (int i = 0; i < 4; i++) {
        const int gmBase = bm + wm + i * 16 + (lane >> 4) * 4;
#pragma unroll
        for (int j = 0; j < 4; j++) {
            const int gn = bn + wn + j * 16 + (lane & 15);
            const float bvj = bias[gn];
#pragma unroll
            for (int r = 0; r < 4; r++)
                C[(size_t)(gmBase + r) * N + gn] = acc[i][j][r] + bvj;
        }
    }
}

// Dilated attention: 4 rows per wave; lane group g=lane>>4 owns row i0+g,
// lane&15 owns 4 head-dims (bf16x4). q,k,v: [B,H,N,64] bf16 (q,k normalized).
__global__ __launch_bounds__(256) void attn_sparse(
    const __bf16* __restrict__ q, const __bf16* __restrict__ k,
    const __bf16* __restrict__ v, __bf16* __restrict__ ao /*[B,N,D] bf16*/)
{
    const int wid  = blockIdx.x * 4 + (threadIdx.x >> 6);
    const int lane = threadIdx.x & 63;
    const int g    = lane >> 4;
    const int ld   = (lane & 15) * 4;

    const int bh = wid >> 9;            // 512 wave-tasks per (b,h)
    const int i  = (wid & 511) * 4 + g; // this lane-group's row

    const __bf16* qb = q + (size_t)bh * 2048 * 64;
    const __bf16* kb = k + (size_t)bh * 2048 * 64;
    const __bf16* vb = v + (size_t)bh * 2048 * 64;

    bf16x4 qv = *(const bf16x4*)(qb + (size_t)i * 64 + ld);
    float q0 = (float)qv[0], q1 = (float)qv[1], q2 = (float)qv[2], q3 = (float)qv[3];

    float s[17];
#pragma unroll
    for (int t = 0; t < 17; t++) {
        const int j = i + 2 * t - 16;
        const bool valid = (j >= 0) && (j < 2048);
        const int jc = valid ? j : i;
        bf16x4 kv = *(const bf16x4*)(kb + (size_t)jc * 64 + ld);
        float prod = q0 * (float)kv[0];
        prod = fmaf(q1, (float)kv[1], prod);
        prod = fmaf(q2, (float)kv[2], prod);
        prod = fmaf(q3, (float)kv[3], prod);
        prod += __shfl_xor(prod, 1);
        prod += __shfl_xor(prod, 2);
        prod += __shfl_xor(prod, 4);
        prod += __shfl_xor(prod, 8);
        s[t] = valid ? prod : -INFINITY;
    }

    float m = s[0];
#pragma unroll
    for (int t = 1; t < 17; t++) m = fmaxf(m, s[t]);
    float denom = 0.f, p[17];
#pragma unroll
    for (int t = 0; t < 17; t++) { p[t] = __expf(s[t] - m); denom += p[t]; }
    const float inv = 1.0f / denom;

    float a0 = 0.f, a1 = 0.f, a2 = 0.f, a3 = 0.f;
#pragma unroll
    for (int t = 0; t < 17; t++) {
        const int j = i + 2 * t - 16;
        const int jc = (j >= 0 && j < 2048) ? j : i;   // p[t]==0 when invalid
        bf16x4 vv = *(const bf16x4*)(vb + (size_t)jc * 64 + ld);
        a0 = fmaf(p[t], (float)vv[0], a0);
        a1 = fmaf(p[t], (float)vv[1], a1);
        a2 = fmaf(p[t], (float)vv[2], a2);
        a3 = fmaf(p[t], (float)vv[3], a3);
    }

    const int b = bh >> 4, h = bh & 15;
    bf16x4 o;
    o[0] = (__bf16)(a0 * inv); o[1] = (__bf16)(a1 * inv);
    o[2] = (__bf16)(a2 * inv); o[3] = (__bf16)(a3 * inv);
    *(bf16x4*)(ao + ((size_t)(b * 2048 + i)) * 1024 + h * 64 + ld) = o;
}

extern "C" void kernel_launch(void* const* d_in, const int* in_sizes, int n_in,
                              void* d_out, int out_size, void* d_ws, size_t ws_size,
                              hipStream_t stream)
{
    const float* x     = (const float*)d_in[0];  // [2,2048,1024]
    const float* w_qkv = (const float*)d_in[1];  // [3072,1024]
    const float* b_qkv = (const float*)d_in[2];  // [3072]
    const float* w_out = (const float*)d_in[3];  // [1024,1024]
    const float* b_out = (const float*)d_in[4];  // [1024]
    float* out = (float*)d_out;                  // [2,2048,1024]

    const int Dn = 1024;
    const int M  = 4096;
    const int nx = 4194304, nwq = 3145728, nwo = 1048576;

    char* p = (char*)d_ws;
    __bf16* q   = (__bf16*)p;  p += (size_t)nx * 2;   // [2,16,2048,64]
    __bf16* kk  = (__bf16*)p;  p += (size_t)nx * 2;
    __bf16* vv  = (__bf16*)p;  p += (size_t)nx * 2;
    __bf16* xh  = (__bf16*)p;  p += (size_t)nx * 2;   // aliased to ao after gemm_qkv
    __bf16* xl  = (__bf16*)p;  p += (size_t)nx * 2;
    __bf16* wqh = (__bf16*)p;  p += (size_t)nwq * 2;
    __bf16* wql = (__bf16*)p;  p += (size_t)nwq * 2;
    __bf16* woh = (__bf16*)p;  p += (size_t)nwo * 2;
    __bf16* wol = (__bf16*)p;  p += (size_t)nwo * 2;
    __bf16* ao  = xh;

    // 0) split fp32 -> hi/lo bf16
    {
        dim3 grid(nx / 8 / 256, 3);
        hipLaunchKernelGGL(split_mat, grid, dim3(256), 0, stream,
                           x, xh, xl, nx,
                           w_qkv, wqh, wql, nwq,
                           w_out, woh, wol, nwo);
    }
    // 1) qkv projection + fused qk-norm -> q,k,v bf16 head layout
    {
        dim3 grid(3 * Dn / TN, M / TM);
        hipLaunchKernelGGL(gemm_qkv, grid, dim3(256), 0, stream,
                           xh, xl, wqh, wql, b_qkv, q, kk, vv, M, 3 * Dn, Dn);
    }
    // 2) sparse dilated attention -> ao bf16 [B,N,D]
    hipLaunchKernelGGL(attn_sparse, dim3(65536 / 16), dim3(256), 0, stream,
                       q, kk, vv, ao);
    // 3) output projection (2-term) -> fp32 out
    {
        dim3 grid(Dn / TN, M / TM);
        hipLaunchKernelGGL(gemm_out, grid, dim3(256), 0, stream,
                           ao, woh, wol, b_out, out, M, Dn, Dn);
    }
}

// Round 5
// 220.803 us; speedup vs baseline: 3.7204x; 1.0905x over previous
//
#include <hip/hip_runtime.h>
#include <hip/hip_bf16.h>
#include <math.h>

typedef __bf16 bf16x8 __attribute__((ext_vector_type(8)));
typedef __bf16 bf16x4 __attribute__((ext_vector_type(4)));
typedef float f32x4 __attribute__((ext_vector_type(4)));

#define TM 128
#define TN 128
#define BK 32  // bf16 elements per K-tile

__device__ inline void async16(const void* g, void* l) {
    __builtin_amdgcn_global_load_lds(
        (const __attribute__((address_space(1))) unsigned int*)g,
        (__attribute__((address_space(3))) unsigned int*)l, 16, 0, 0);
}

// stage one TMxBK bf16 tile: 512 16B chunks, this thread covers chunks c0 and c1
__device__ inline void stage_tile(__bf16* S, const __bf16* G, int row0, int K, int k0,
                                  int c0, int r0, int b0, int c1, int r1, int b1) {
    const char* g0 = (const char*)G + ((size_t)(row0 + r0) * K + k0) * 2 + b0;
    const char* g1 = (const char*)G + ((size_t)(row0 + r1) * K + k0) * 2 + b1;
    async16(g0, (char*)S + c0 * 16);
    async16(g1, (char*)S + c1 * 16);
}

// fp32 -> bf16 hi (+ optional lo). blockIdx.y selects {x(h only), w_qkv, w_out}.
__global__ __launch_bounds__(256) void split_mat(
    const float* __restrict__ s0, __bf16* __restrict__ h0, __bf16* __restrict__ l0, int n0,
    const float* __restrict__ s1, __bf16* __restrict__ h1, __bf16* __restrict__ l1, int n1,
    const float* __restrict__ s2, __bf16* __restrict__ h2, __bf16* __restrict__ l2, int n2)
{
    const float* s; __bf16* h; __bf16* l; int n;
    if (blockIdx.y == 0)      { s = s0; h = h0; l = l0; n = n0; }
    else if (blockIdx.y == 1) { s = s1; h = h1; l = l1; n = n1; }
    else                      { s = s2; h = h2; l = l2; n = n2; }
    const int base = (blockIdx.x * 256 + threadIdx.x) * 8;
    if (base >= n) return;
    float4 a = ((const float4*)(s + base))[0];
    float4 b = ((const float4*)(s + base))[1];
    float buf[8] = {a.x, a.y, a.z, a.w, b.x, b.y, b.z, b.w};
    bf16x8 hv, lv;
#pragma unroll
    for (int j = 0; j < 8; j++) {
        __bf16 hb = (__bf16)buf[j];
        hv[j] = hb;
        lv[j] = (__bf16)(buf[j] - (float)hb);
    }
    *(bf16x8*)(h + base) = hv;
    if (l) *(bf16x8*)(l + base) = lv;
}

// QKV projection: C = A(Wh+Wl)^T + bias (2-term MFMA, A plain bf16),
// fused QK-norm, scatter q/k/v bf16 into [B,H,N,64].
__global__ __launch_bounds__(256) void gemm_qkv(
    const __bf16* __restrict__ A,
    const __bf16* __restrict__ Wh, const __bf16* __restrict__ Wl,
    const float* __restrict__ bias,
    __bf16* __restrict__ q, __bf16* __restrict__ k, __bf16* __restrict__ v,
    int M, int N, int K)
{
    __shared__ __bf16 sA[TM][BK];
    __shared__ __bf16 sWh[TN][BK];
    __shared__ __bf16 sWl[TN][BK];

    const int tid  = threadIdx.x;
    const int lane = tid & 63;
    const int wave = tid >> 6;
    const int bm = blockIdx.y * TM;
    const int bn = blockIdx.x * TN;
    const int wm = (wave >> 1) * 64;
    const int wn = (wave & 1) * 64;
    const int frow = lane & 15;
    const int fk   = (lane >> 4) * 8;

    const int c0 = tid, c1 = tid + 256;
    const int r0 = c0 >> 2, b0 = (c0 & 3) * 16;
    const int r1 = c1 >> 2, b1 = (c1 & 3) * 16;

    f32x4 acc[4][4] = {};

    for (int k0 = 0; k0 < K; k0 += BK) {
        stage_tile(&sA[0][0],  A,  bm, K, k0, c0, r0, b0, c1, r1, b1);
        stage_tile(&sWh[0][0], Wh, bn, K, k0, c0, r0, b0, c1, r1, b1);
        stage_tile(&sWl[0][0], Wl, bn, K, k0, c0, r0, b0, c1, r1, b1);
        __syncthreads();

        bf16x8 aH[4], bH[4], bL[4];
#pragma unroll
        for (int t = 0; t < 4; t++) {
            aH[t] = *(const bf16x8*)&sA[wm + t * 16 + frow][fk];
            bH[t] = *(const bf16x8*)&sWh[wn + t * 16 + frow][fk];
            bL[t] = *(const bf16x8*)&sWl[wn + t * 16 + frow][fk];
        }
#pragma unroll
        for (int i = 0; i < 4; i++)
#pragma unroll
            for (int j = 0; j < 4; j++) {
                acc[i][j] = __builtin_amdgcn_mfma_f32_16x16x32_bf16(aH[i], bH[j], acc[i][j], 0, 0, 0);
                acc[i][j] = __builtin_amdgcn_mfma_f32_16x16x32_bf16(aH[i], bL[j], acc[i][j], 0, 0, 0);
            }
        __syncthreads();
    }

    // wave's 64-col window = exactly one (tensor t, head h)
    const int col0 = bn + wn;
    const int t  = col0 >> 10;            // 0=q 1=k 2=v
    const int h  = (col0 & 1023) >> 6;

    float bv[4];
#pragma unroll
    for (int j = 0; j < 4; j++) bv[j] = bias[col0 + j * 16 + (lane & 15)];

    // fused QK-norm: per output row, 1/(||row||+eps); row spread over j regs x 16 lanes
    float inv_n[4][4];
    if (t < 2) {
#pragma unroll
        for (int i = 0; i < 4; i++)
#pragma unroll
            for (int r = 0; r < 4; r++) {
                float ss = 0.f;
#pragma unroll
                for (int j = 0; j < 4; j++) {
                    float val = acc[i][j][r] + bv[j];
                    ss = fmaf(val, val, ss);
                }
                ss += __shfl_xor(ss, 1);
                ss += __shfl_xor(ss, 2);
                ss += __shfl_xor(ss, 4);
                ss += __shfl_xor(ss, 8);
                inv_n[i][r] = 1.0f / (sqrtf(ss) + 1e-6f);
            }
    }

    __bf16* dstbase = (t == 0) ? q : (t == 1) ? k : v;
#pragma unroll
    for (int i = 0; i < 4; i++) {
        const int gmBase = bm + wm + i * 16 + (lane >> 4) * 4;
#pragma unroll
        for (int j = 0; j < 4; j++) {
            const int dd = (wn & 63) + j * 16 + (lane & 15); // 0..63 within head
#pragma unroll
            for (int r = 0; r < 4; r++) {
                const int gm = gmBase + r;
                float val = acc[i][j][r] + bv[j];
                if (t < 2) val *= inv_n[i][r];
                const int b  = gm >> 11;
                const int ii = gm & 2047;
                const size_t dst = (((size_t)(b * 16 + h) * 2048) + ii) * 64 + dd;
                dstbase[dst] = (__bf16)val;
            }
        }
    }
}

// Out projection: C = A(Wh+Wl)^T + bias, A plain bf16 (2-term MFMA), fp32 out.
__global__ __launch_bounds__(256) void gemm_out(
    const __bf16* __restrict__ A,
    const __bf16* __restrict__ Wh, const __bf16* __restrict__ Wl,
    const float* __restrict__ bias, float* __restrict__ C,
    int M, int N, int K)
{
    __shared__ __bf16 sA[TM][BK];
    __shared__ __bf16 sWh[TN][BK];
    __shared__ __bf16 sWl[TN][BK];

    const int tid  = threadIdx.x;
    const int lane = tid & 63;
    const int wave = tid >> 6;
    const int bm = blockIdx.y * TM;
    const int bn = blockIdx.x * TN;
    const int wm = (wave >> 1) * 64;
    const int wn = (wave & 1) * 64;
    const int frow = lane & 15;
    const int fk   = (lane >> 4) * 8;

    const int c0 = tid, c1 = tid + 256;
    const int r0 = c0 >> 2, b0 = (c0 & 3) * 16;
    const int r1 = c1 >> 2, b1 = (c1 & 3) * 16;

    f32x4 acc[4][4] = {};

    for (int k0 = 0; k0 < K; k0 += BK) {
        stage_tile(&sA[0][0],  A,  bm, K, k0, c0, r0, b0, c1, r1, b1);
        stage_tile(&sWh[0][0], Wh, bn, K, k0, c0, r0, b0, c1, r1, b1);
        stage_tile(&sWl[0][0], Wl, bn, K, k0, c0, r0, b0, c1, r1, b1);
        __syncthreads();

        bf16x8 aH[4], bH[4], bL[4];
#pragma unroll
        for (int t = 0; t < 4; t++) {
            aH[t] = *(const bf16x8*)&sA[wm + t * 16 + frow][fk];
            bH[t] = *(const bf16x8*)&sWh[wn + t * 16 + frow][fk];
            bL[t] = *(const bf16x8*)&sWl[wn + t * 16 + frow][fk];
        }
#pragma unroll
        for (int i = 0; i < 4; i++)
#pragma unroll
            for (int j = 0; j < 4; j++) {
                acc[i][j] = __builtin_amdgcn_mfma_f32_16x16x32_bf16(aH[i], bH[j], acc[i][j], 0, 0, 0);
                acc[i][j] = __builtin_amdgcn_mfma_f32_16x16x32_bf16(aH[i], bL[j], acc[i][j], 0, 0, 0);
            }
        __syncthreads();
    }

#pragma unroll
    for (int i = 0; i < 4; i++) {
        const int gmBase = bm + wm + i * 16 + (lane >> 4) * 4;
#pragma unroll
        for (int j = 0; j < 4; j++) {
            const int gn = bn + wn + j * 16 + (lane & 15);
            const float bvj = bias[gn];
#pragma unroll
            for (int r = 0; r < 4; r++)
                C[(size_t)(gmBase + r) * N + gn] = acc[i][j][r] + bvj;
        }
    }
}

// Dilated attention: 4 rows per wave; lane group g=lane>>4 owns row i0+g,
// lane&15 owns 4 head-dims (bf16x4). q,k,v: [B,H,N,64] bf16 (q,k normalized).
__global__ __launch_bounds__(256) void attn_sparse(
    const __bf16* __restrict__ q, const __bf16* __restrict__ k,
    const __bf16* __restrict__ v, __bf16* __restrict__ ao /*[B,N,D] bf16*/)
{
    const int wid  = blockIdx.x * 4 + (threadIdx.x >> 6);
    const int lane = threadIdx.x & 63;
    const int g    = lane >> 4;
    const int ld   = (lane & 15) * 4;

    const int bh = wid >> 9;            // 512 wave-tasks per (b,h)
    const int i  = (wid & 511) * 4 + g; // this lane-group's row

    const __bf16* qb = q + (size_t)bh * 2048 * 64;
    const __bf16* kb = k + (size_t)bh * 2048 * 64;
    const __bf16* vb = v + (size_t)bh * 2048 * 64;

    bf16x4 qv = *(const bf16x4*)(qb + (size_t)i * 64 + ld);
    float q0 = (float)qv[0], q1 = (float)qv[1], q2 = (float)qv[2], q3 = (float)qv[3];

    float s[17];
#pragma unroll
    for (int t = 0; t < 17; t++) {
        const int j = i + 2 * t - 16;
        const bool valid = (j >= 0) && (j < 2048);
        const int jc = valid ? j : i;
        bf16x4 kv = *(const bf16x4*)(kb + (size_t)jc * 64 + ld);
        float prod = q0 * (float)kv[0];
        prod = fmaf(q1, (float)kv[1], prod);
        prod = fmaf(q2, (float)kv[2], prod);
        prod = fmaf(q3, (float)kv[3], prod);
        prod += __shfl_xor(prod, 1);
        prod += __shfl_xor(prod, 2);
        prod += __shfl_xor(prod, 4);
        prod += __shfl_xor(prod, 8);
        s[t] = valid ? prod : -INFINITY;
    }

    float m = s[0];
#pragma unroll
    for (int t = 1; t < 17; t++) m = fmaxf(m, s[t]);
    float denom = 0.f, p[17];
#pragma unroll
    for (int t = 0; t < 17; t++) { p[t] = __expf(s[t] - m); denom += p[t]; }
    const float inv = 1.0f / denom;

    float a0 = 0.f, a1 = 0.f, a2 = 0.f, a3 = 0.f;
#pragma unroll
    for (int t = 0; t < 17; t++) {
        const int j = i + 2 * t - 16;
        const int jc = (j >= 0 && j < 2048) ? j : i;   // p[t]==0 when invalid
        bf16x4 vv = *(const bf16x4*)(vb + (size_t)jc * 64 + ld);
        a0 = fmaf(p[t], (float)vv[0], a0);
        a1 = fmaf(p[t], (float)vv[1], a1);
        a2 = fmaf(p[t], (float)vv[2], a2);
        a3 = fmaf(p[t], (float)vv[3], a3);
    }

    const int b = bh >> 4, h = bh & 15;
    bf16x4 o;
    o[0] = (__bf16)(a0 * inv); o[1] = (__bf16)(a1 * inv);
    o[2] = (__bf16)(a2 * inv); o[3] = (__bf16)(a3 * inv);
    *(bf16x4*)(ao + ((size_t)(b * 2048 + i)) * 1024 + h * 64 + ld) = o;
}

extern "C" void kernel_launch(void* const* d_in, const int* in_sizes, int n_in,
                              void* d_out, int out_size, void* d_ws, size_t ws_size,
                              hipStream_t stream)
{
    const float* x     = (const float*)d_in[0];  // [2,2048,1024]
    const float* w_qkv = (const float*)d_in[1];  // [3072,1024]
    const float* b_qkv = (const float*)d_in[2];  // [3072]
    const float* w_out = (const float*)d_in[3];  // [1024,1024]
    const float* b_out = (const float*)d_in[4];  // [1024]
    float* out = (float*)d_out;                  // [2,2048,1024]

    const int Dn = 1024;
    const int M  = 4096;
    const int nx = 4194304, nwq = 3145728, nwo = 1048576;

    char* p = (char*)d_ws;
    __bf16* q   = (__bf16*)p;  p += (size_t)nx * 2;   // [2,16,2048,64]
    __bf16* kk  = (__bf16*)p;  p += (size_t)nx * 2;
    __bf16* vv  = (__bf16*)p;  p += (size_t)nx * 2;
    __bf16* xh  = (__bf16*)p;  p += (size_t)nx * 2;   // aliased to ao after gemm_qkv
    __bf16* wqh = (__bf16*)p;  p += (size_t)nwq * 2;
    __bf16* wql = (__bf16*)p;  p += (size_t)nwq * 2;
    __bf16* woh = (__bf16*)p;  p += (size_t)nwo * 2;
    __bf16* wol = (__bf16*)p;  p += (size_t)nwo * 2;
    __bf16* ao  = xh;

    // 0) x -> bf16 cast; w_qkv, w_out -> hi/lo bf16 split
    {
        dim3 grid(nx / 8 / 256, 3);
        hipLaunchKernelGGL(split_mat, grid, dim3(256), 0, stream,
                           x, xh, (__bf16*)nullptr, nx,
                           w_qkv, wqh, wql, nwq,
                           w_out, woh, wol, nwo);
    }
    // 1) qkv projection (2-term) + fused qk-norm -> q,k,v bf16 head layout
    {
        dim3 grid(3 * Dn / TN, M / TM);
        hipLaunchKernelGGL(gemm_qkv, grid, dim3(256), 0, stream,
                           xh, wqh, wql, b_qkv, q, kk, vv, M, 3 * Dn, Dn);
    }
    // 2) sparse dilated attention -> ao bf16 [B,N,D]
    hipLaunchKernelGGL(attn_sparse, dim3(65536 / 16), dim3(256), 0, stream,
                       q, kk, vv, ao);
    // 3) output projection (2-term) -> fp32 out
    {
        dim3 grid(Dn / TN, M / TM);
        hipLaunchKernelGGL(gemm_out, grid, dim3(256), 0, stream,
                           ao, woh, wol, b_out, out, M, Dn, Dn);
    }
}

// Round 6
// 180.463 us; speedup vs baseline: 4.5521x; 1.2235x over previous
//
#include <hip/hip_runtime.h>
#include <hip/hip_bf16.h>
#include <math.h>

typedef __bf16 bf16x8 __attribute__((ext_vector_type(8)));
typedef __bf16 bf16x4 __attribute__((ext_vector_type(4)));
typedef float f32x4 __attribute__((ext_vector_type(4)));

#define TM 128
#define BK 64   // bf16 elements per K-tile (8 chunks of 16B per row)

__device__ inline void async16(const void* g, void* l) {
    __builtin_amdgcn_global_load_lds(
        (const __attribute__((address_space(1))) unsigned int*)g,
        (__attribute__((address_space(3))) unsigned int*)l, 16, 0, 0);
}

// Stage a R x 64 bf16 tile with XOR chunk swizzle: LDS chunk (r,c) holds global
// chunk (r, c^(r&7)). Global side stays within the same 128B row segment.
// nchunks = R*8, each thread covers nchunks/256 chunks.
__device__ inline void stage_sw(__bf16* S, const __bf16* G, int row0, int K, int k0,
                                int tid, int nchunks) {
#pragma unroll
    for (int ci = tid; ci < nchunks; ci += 256) {
        const int r  = ci >> 3;
        const int c  = ci & 7;
        const int cg = c ^ (r & 7);
        const char* g = (const char*)G + ((size_t)(row0 + r) * K + k0 + cg * 8) * 2;
        async16(g, (char*)S + ci * 16);
    }
}

// Swizzled fragment read: global chunk (r, cfrag) lives at LDS chunk cfrag^(r&7).
__device__ inline bf16x8 frag_sw(const __bf16* S, int r, int cfrag) {
    const int c = cfrag ^ (r & 7);
    return *(const bf16x8*)(S + r * 64 + c * 8);
}

// fp32 -> bf16 hi (+ optional lo). blockIdx.y selects {x(h only), w_qkv, w_out}.
__global__ __launch_bounds__(256) void split_mat(
    const float* __restrict__ s0, __bf16* __restrict__ h0, __bf16* __restrict__ l0, int n0,
    const float* __restrict__ s1, __bf16* __restrict__ h1, __bf16* __restrict__ l1, int n1,
    const float* __restrict__ s2, __bf16* __restrict__ h2, __bf16* __restrict__ l2, int n2)
{
    const float* s; __bf16* h; __bf16* l; int n;
    if (blockIdx.y == 0)      { s = s0; h = h0; l = l0; n = n0; }
    else if (blockIdx.y == 1) { s = s1; h = h1; l = l1; n = n1; }
    else                      { s = s2; h = h2; l = l2; n = n2; }
    const int base = (blockIdx.x * 256 + threadIdx.x) * 8;
    if (base >= n) return;
    float4 a = ((const float4*)(s + base))[0];
    float4 b = ((const float4*)(s + base))[1];
    float buf[8] = {a.x, a.y, a.z, a.w, b.x, b.y, b.z, b.w};
    bf16x8 hv, lv;
#pragma unroll
    for (int j = 0; j < 8; j++) {
        __bf16 hb = (__bf16)buf[j];
        hv[j] = hb;
        lv[j] = (__bf16)(buf[j] - (float)hb);
    }
    *(bf16x8*)(h + base) = hv;
    if (l) *(bf16x8*)(l + base) = lv;
}

// QKV projection: C = A(Wh+Wl)^T + bias (2-term MFMA, A plain bf16),
// fused QK-norm, scatter q/k/v bf16 into [B,H,N,64]. TN=128.
__global__ __launch_bounds__(256) void gemm_qkv(
    const __bf16* __restrict__ A,
    const __bf16* __restrict__ Wh, const __bf16* __restrict__ Wl,
    const float* __restrict__ bias,
    __bf16* __restrict__ q, __bf16* __restrict__ k, __bf16* __restrict__ v,
    int M, int N, int K)
{
    __shared__ __bf16 sA[TM * BK];
    __shared__ __bf16 sWh[TM * BK];
    __shared__ __bf16 sWl[TM * BK];

    const int tid  = threadIdx.x;
    const int lane = tid & 63;
    const int wave = tid >> 6;
    const int bm = blockIdx.y * TM;
    const int bn = blockIdx.x * 128;
    const int wm = (wave >> 1) * 64;
    const int wn = (wave & 1) * 64;
    const int frow = lane & 15;

    f32x4 acc[4][4] = {};

    for (int k0 = 0; k0 < K; k0 += BK) {
        stage_sw(sA,  A,  bm, K, k0, tid, TM * 8);
        stage_sw(sWh, Wh, bn, K, k0, tid, TM * 8);
        stage_sw(sWl, Wl, bn, K, k0, tid, TM * 8);
        __syncthreads();

#pragma unroll
        for (int half = 0; half < 2; half++) {
            const int cf = half * 4 + (lane >> 4);
            bf16x8 aH[4], bH[4], bL[4];
#pragma unroll
            for (int t = 0; t < 4; t++) {
                aH[t] = frag_sw(sA,  wm + t * 16 + frow, cf);
                bH[t] = frag_sw(sWh, wn + t * 16 + frow, cf);
                bL[t] = frag_sw(sWl, wn + t * 16 + frow, cf);
            }
#pragma unroll
            for (int i = 0; i < 4; i++)
#pragma unroll
                for (int j = 0; j < 4; j++) {
                    acc[i][j] = __builtin_amdgcn_mfma_f32_16x16x32_bf16(aH[i], bH[j], acc[i][j], 0, 0, 0);
                    acc[i][j] = __builtin_amdgcn_mfma_f32_16x16x32_bf16(aH[i], bL[j], acc[i][j], 0, 0, 0);
                }
        }
        __syncthreads();
    }

    // wave's 64-col window = exactly one (tensor t, head h)
    const int col0 = bn + wn;
    const int t  = col0 >> 10;            // 0=q 1=k 2=v
    const int h  = (col0 & 1023) >> 6;

    float bv[4];
#pragma unroll
    for (int j = 0; j < 4; j++) bv[j] = bias[col0 + j * 16 + (lane & 15)];

    // fused QK-norm: per output row, 1/(||row||+eps)
    float inv_n[4][4];
    if (t < 2) {
#pragma unroll
        for (int i = 0; i < 4; i++)
#pragma unroll
            for (int r = 0; r < 4; r++) {
                float ss = 0.f;
#pragma unroll
                for (int j = 0; j < 4; j++) {
                    float val = acc[i][j][r] + bv[j];
                    ss = fmaf(val, val, ss);
                }
                ss += __shfl_xor(ss, 1);
                ss += __shfl_xor(ss, 2);
                ss += __shfl_xor(ss, 4);
                ss += __shfl_xor(ss, 8);
                inv_n[i][r] = 1.0f / (sqrtf(ss) + 1e-6f);
            }
    }

    __bf16* dstbase = (t == 0) ? q : (t == 1) ? k : v;
#pragma unroll
    for (int i = 0; i < 4; i++) {
        const int gmBase = bm + wm + i * 16 + (lane >> 4) * 4;
#pragma unroll
        for (int j = 0; j < 4; j++) {
            const int dd = (wn & 63) + j * 16 + (lane & 15);
#pragma unroll
            for (int r = 0; r < 4; r++) {
                const int gm = gmBase + r;
                float val = acc[i][j][r] + bv[j];
                if (t < 2) val *= inv_n[i][r];
                const int b  = gm >> 11;
                const int ii = gm & 2047;
                const size_t dst = (((size_t)(b * 16 + h) * 2048) + ii) * 64 + dd;
                dstbase[dst] = (__bf16)val;
            }
        }
    }
}

// Out projection: C = A(Wh+Wl)^T + bias, A bf16 (2-term), fp32 out.
// TM=128, TN=64 -> 512 blocks (2/CU). Wave owns 64x32.
__global__ __launch_bounds__(256) void gemm_out(
    const __bf16* __restrict__ A,
    const __bf16* __restrict__ Wh, const __bf16* __restrict__ Wl,
    const float* __restrict__ bias, float* __restrict__ C,
    int M, int N, int K)
{
    __shared__ __bf16 sA[TM * BK];
    __shared__ __bf16 sWh[64 * BK];
    __shared__ __bf16 sWl[64 * BK];

    const int tid  = threadIdx.x;
    const int lane = tid & 63;
    const int wave = tid >> 6;
    const int bm = blockIdx.y * TM;
    const int bn = blockIdx.x * 64;
    const int wm = (wave >> 1) * 64;
    const int wn = (wave & 1) * 32;
    const int frow = lane & 15;

    f32x4 acc[4][2] = {};

    for (int k0 = 0; k0 < K; k0 += BK) {
        stage_sw(sA,  A,  bm, K, k0, tid, TM * 8);
        stage_sw(sWh, Wh, bn, K, k0, tid, 64 * 8);
        stage_sw(sWl, Wl, bn, K, k0, tid, 64 * 8);
        __syncthreads();

#pragma unroll
        for (int half = 0; half < 2; half++) {
            const int cf = half * 4 + (lane >> 4);
            bf16x8 aH[4], bH[2], bL[2];
#pragma unroll
            for (int t = 0; t < 4; t++)
                aH[t] = frag_sw(sA, wm + t * 16 + frow, cf);
#pragma unroll
            for (int t = 0; t < 2; t++) {
                bH[t] = frag_sw(sWh, wn + t * 16 + frow, cf);
                bL[t] = frag_sw(sWl, wn + t * 16 + frow, cf);
            }
#pragma unroll
            for (int i = 0; i < 4; i++)
#pragma unroll
                for (int j = 0; j < 2; j++) {
                    acc[i][j] = __builtin_amdgcn_mfma_f32_16x16x32_bf16(aH[i], bH[j], acc[i][j], 0, 0, 0);
                    acc[i][j] = __builtin_amdgcn_mfma_f32_16x16x32_bf16(aH[i], bL[j], acc[i][j], 0, 0, 0);
                }
        }
        __syncthreads();
    }

#pragma unroll
    for (int i = 0; i < 4; i++) {
        const int gmBase = bm + wm + i * 16 + (lane >> 4) * 4;
#pragma unroll
        for (int j = 0; j < 2; j++) {
            const int gn = bn + wn + j * 16 + (lane & 15);
            const float bvj = bias[gn];
#pragma unroll
            for (int r = 0; r < 4; r++)
                C[(size_t)(gmBase + r) * N + gn] = acc[i][j][r] + bvj;
        }
    }
}

// Dilated attention: 4 rows per wave; lane group g=lane>>4 owns row i0+g,
// lane&15 owns 4 head-dims (bf16x4). q,k,v: [B,H,N,64] bf16 (q,k normalized).
__global__ __launch_bounds__(256) void attn_sparse(
    const __bf16* __restrict__ q, const __bf16* __restrict__ k,
    const __bf16* __restrict__ v, __bf16* __restrict__ ao /*[B,N,D] bf16*/)
{
    const int wid  = blockIdx.x * 4 + (threadIdx.x >> 6);
    const int lane = threadIdx.x & 63;
    const int g    = lane >> 4;
    const int ld   = (lane & 15) * 4;

    const int bh = wid >> 9;            // 512 wave-tasks per (b,h)
    const int i  = (wid & 511) * 4 + g; // this lane-group's row

    const __bf16* qb = q + (size_t)bh * 2048 * 64;
    const __bf16* kb = k + (size_t)bh * 2048 * 64;
    const __bf16* vb = v + (size_t)bh * 2048 * 64;

    bf16x4 qv = *(const bf16x4*)(qb + (size_t)i * 64 + ld);
    float q0 = (float)qv[0], q1 = (float)qv[1], q2 = (float)qv[2], q3 = (float)qv[3];

    float s[17];
#pragma unroll
    for (int t = 0; t < 17; t++) {
        const int j = i + 2 * t - 16;
        const bool valid = (j >= 0) && (j < 2048);
        const int jc = valid ? j : i;
        bf16x4 kv = *(const bf16x4*)(kb + (size_t)jc * 64 + ld);
        float prod = q0 * (float)kv[0];
        prod = fmaf(q1, (float)kv[1], prod);
        prod = fmaf(q2, (float)kv[2], prod);
        prod = fmaf(q3, (float)kv[3], prod);
        prod += __shfl_xor(prod, 1);
        prod += __shfl_xor(prod, 2);
        prod += __shfl_xor(prod, 4);
        prod += __shfl_xor(prod, 8);
        s[t] = valid ? prod : -INFINITY;
    }

    float m = s[0];
#pragma unroll
    for (int t = 1; t < 17; t++) m = fmaxf(m, s[t]);
    float denom = 0.f, p[17];
#pragma unroll
    for (int t = 0; t < 17; t++) { p[t] = __expf(s[t] - m); denom += p[t]; }
    const float inv = 1.0f / denom;

    float a0 = 0.f, a1 = 0.f, a2 = 0.f, a3 = 0.f;
#pragma unroll
    for (int t = 0; t < 17; t++) {
        const int j = i + 2 * t - 16;
        const int jc = (j >= 0 && j < 2048) ? j : i;   // p[t]==0 when invalid
        bf16x4 vv = *(const bf16x4*)(vb + (size_t)jc * 64 + ld);
        a0 = fmaf(p[t], (float)vv[0], a0);
        a1 = fmaf(p[t], (float)vv[1], a1);
        a2 = fmaf(p[t], (float)vv[2], a2);
        a3 = fmaf(p[t], (float)vv[3], a3);
    }

    const int b = bh >> 4, h = bh & 15;
    bf16x4 o;
    o[0] = (__bf16)(a0 * inv); o[1] = (__bf16)(a1 * inv);
    o[2] = (__bf16)(a2 * inv); o[3] = (__bf16)(a3 * inv);
    *(bf16x4*)(ao + ((size_t)(b * 2048 + i)) * 1024 + h * 64 + ld) = o;
}

extern "C" void kernel_launch(void* const* d_in, const int* in_sizes, int n_in,
                              void* d_out, int out_size, void* d_ws, size_t ws_size,
                              hipStream_t stream)
{
    const float* x     = (const float*)d_in[0];  // [2,2048,1024]
    const float* w_qkv = (const float*)d_in[1];  // [3072,1024]
    const float* b_qkv = (const float*)d_in[2];  // [3072]
    const float* w_out = (const float*)d_in[3];  // [1024,1024]
    const float* b_out = (const float*)d_in[4];  // [1024]
    float* out = (float*)d_out;                  // [2,2048,1024]

    const int Dn = 1024;
    const int M  = 4096;
    const int nx = 4194304, nwq = 3145728, nwo = 1048576;

    char* p = (char*)d_ws;
    __bf16* q   = (__bf16*)p;  p += (size_t)nx * 2;   // [2,16,2048,64]
    __bf16* kk  = (__bf16*)p;  p += (size_t)nx * 2;
    __bf16* vv  = (__bf16*)p;  p += (size_t)nx * 2;
    __bf16* xh  = (__bf16*)p;  p += (size_t)nx * 2;   // aliased to ao after gemm_qkv
    __bf16* wqh = (__bf16*)p;  p += (size_t)nwq * 2;
    __bf16* wql = (__bf16*)p;  p += (size_t)nwq * 2;
    __bf16* woh = (__bf16*)p;  p += (size_t)nwo * 2;
    __bf16* wol = (__bf16*)p;  p += (size_t)nwo * 2;
    __bf16* ao  = xh;

    // 0) x -> bf16 cast; w_qkv, w_out -> hi/lo bf16 split
    {
        dim3 grid(nx / 8 / 256, 3);
        hipLaunchKernelGGL(split_mat, grid, dim3(256), 0, stream,
                           x, xh, (__bf16*)nullptr, nx,
                           w_qkv, wqh, wql, nwq,
                           w_out, woh, wol, nwo);
    }
    // 1) qkv projection (2-term) + fused qk-norm -> q,k,v bf16 head layout
    {
        dim3 grid(3 * Dn / 128, M / TM);
        hipLaunchKernelGGL(gemm_qkv, grid, dim3(256), 0, stream,
                           xh, wqh, wql, b_qkv, q, kk, vv, M, 3 * Dn, Dn);
    }
    // 2) sparse dilated attention -> ao bf16 [B,N,D]
    hipLaunchKernelGGL(attn_sparse, dim3(65536 / 16), dim3(256), 0, stream,
                       q, kk, vv, ao);
    // 3) output projection (2-term) -> fp32 out
    {
        dim3 grid(Dn / 64, M / TM);
        hipLaunchKernelGGL(gemm_out, grid, dim3(256), 0, stream,
                           ao, woh, wol, b_out, out, M, Dn, Dn);
    }
}

// Round 7
// 163.167 us; speedup vs baseline: 5.0346x; 1.1060x over previous
//
#include <hip/hip_runtime.h>
#include <hip/hip_bf16.h>
#include <math.h>

typedef __bf16 bf16x8 __attribute__((ext_vector_type(8)));
typedef __bf16 bf16x4 __attribute__((ext_vector_type(4)));
typedef float f32x4 __attribute__((ext_vector_type(4)));

#define TM 128
#define BK 64   // bf16 elements per K-tile (8 chunks of 16B per row)

__device__ inline void async16(const void* g, void* l) {
    __builtin_amdgcn_global_load_lds(
        (const __attribute__((address_space(1))) unsigned int*)g,
        (__attribute__((address_space(3))) unsigned int*)l, 16, 0, 0);
}

// Stage a R x 64 bf16 tile with XOR chunk swizzle: LDS chunk (r,c) holds global
// chunk (r, c^(r&7)). Readers then hit all 32 banks (2-way = free).
__device__ inline void stage_sw(__bf16* S, const __bf16* G, int row0, int K, int k0,
                                int tid, int nchunks) {
#pragma unroll
    for (int ci = tid; ci < nchunks; ci += 256) {
        const int r  = ci >> 3;
        const int c  = ci & 7;
        const int cg = c ^ (r & 7);
        const char* g = (const char*)G + ((size_t)(row0 + r) * K + k0 + cg * 8) * 2;
        async16(g, (char*)S + ci * 16);
    }
}

// Swizzled fragment read: global chunk (r, cfrag) lives at LDS chunk cfrag^(r&7).
__device__ inline bf16x8 frag_sw(const __bf16* S, int r, int cfrag) {
    const int c = cfrag ^ (r & 7);
    return *(const bf16x8*)(S + r * 64 + c * 8);
}

// fp32 -> bf16 hi (+ optional lo). blockIdx.y selects {x, w_qkv, w_out}.
__global__ __launch_bounds__(256) void split_mat(
    const float* __restrict__ s0, __bf16* __restrict__ h0, __bf16* __restrict__ l0, int n0,
    const float* __restrict__ s1, __bf16* __restrict__ h1, __bf16* __restrict__ l1, int n1,
    const float* __restrict__ s2, __bf16* __restrict__ h2, __bf16* __restrict__ l2, int n2)
{
    const float* s; __bf16* h; __bf16* l; int n;
    if (blockIdx.y == 0)      { s = s0; h = h0; l = l0; n = n0; }
    else if (blockIdx.y == 1) { s = s1; h = h1; l = l1; n = n1; }
    else                      { s = s2; h = h2; l = l2; n = n2; }
    const int base = (blockIdx.x * 256 + threadIdx.x) * 8;
    if (base >= n) return;
    float4 a = ((const float4*)(s + base))[0];
    float4 b = ((const float4*)(s + base))[1];
    float buf[8] = {a.x, a.y, a.z, a.w, b.x, b.y, b.z, b.w};
    bf16x8 hv, lv;
#pragma unroll
    for (int j = 0; j < 8; j++) {
        __bf16 hb = (__bf16)buf[j];
        hv[j] = hb;
        lv[j] = (__bf16)(buf[j] - (float)hb);
    }
    *(bf16x8*)(h + base) = hv;
    if (l) *(bf16x8*)(l + base) = lv;
}

// QKV projection: C = A*W^T + bias (plain bf16 1-term MFMA),
// fused QK-norm, scatter q/k/v bf16 into [B,H,N,64]. TN=128.
__global__ __launch_bounds__(256) void gemm_qkv(
    const __bf16* __restrict__ A, const __bf16* __restrict__ W,
    const float* __restrict__ bias,
    __bf16* __restrict__ q, __bf16* __restrict__ k, __bf16* __restrict__ v,
    int M, int N, int K)
{
    __shared__ __bf16 sA[TM * BK];
    __shared__ __bf16 sW[TM * BK];

    const int tid  = threadIdx.x;
    const int lane = tid & 63;
    const int wave = tid >> 6;
    const int bm = blockIdx.y * TM;
    const int bn = blockIdx.x * 128;
    const int wm = (wave >> 1) * 64;
    const int wn = (wave & 1) * 64;
    const int frow = lane & 15;

    f32x4 acc[4][4] = {};

    for (int k0 = 0; k0 < K; k0 += BK) {
        stage_sw(sA, A, bm, K, k0, tid, TM * 8);
        stage_sw(sW, W, bn, K, k0, tid, TM * 8);
        __syncthreads();

#pragma unroll
        for (int half = 0; half < 2; half++) {
            const int cf = half * 4 + (lane >> 4);
            bf16x8 aF[4], bF[4];
#pragma unroll
            for (int t = 0; t < 4; t++) {
                aF[t] = frag_sw(sA, wm + t * 16 + frow, cf);
                bF[t] = frag_sw(sW, wn + t * 16 + frow, cf);
            }
#pragma unroll
            for (int i = 0; i < 4; i++)
#pragma unroll
                for (int j = 0; j < 4; j++)
                    acc[i][j] = __builtin_amdgcn_mfma_f32_16x16x32_bf16(aF[i], bF[j], acc[i][j], 0, 0, 0);
        }
        __syncthreads();
    }

    // wave's 64-col window = exactly one (tensor t, head h)
    const int col0 = bn + wn;
    const int t  = col0 >> 10;            // 0=q 1=k 2=v
    const int h  = (col0 & 1023) >> 6;

    float bv[4];
#pragma unroll
    for (int j = 0; j < 4; j++) bv[j] = bias[col0 + j * 16 + (lane & 15)];

    // fused QK-norm: per output row, 1/(||row||+eps)
    float inv_n[4][4];
    if (t < 2) {
#pragma unroll
        for (int i = 0; i < 4; i++)
#pragma unroll
            for (int r = 0; r < 4; r++) {
                float ss = 0.f;
#pragma unroll
                for (int j = 0; j < 4; j++) {
                    float val = acc[i][j][r] + bv[j];
                    ss = fmaf(val, val, ss);
                }
                ss += __shfl_xor(ss, 1);
                ss += __shfl_xor(ss, 2);
                ss += __shfl_xor(ss, 4);
                ss += __shfl_xor(ss, 8);
                inv_n[i][r] = 1.0f / (sqrtf(ss) + 1e-6f);
            }
    }

    __bf16* dstbase = (t == 0) ? q : (t == 1) ? k : v;
#pragma unroll
    for (int i = 0; i < 4; i++) {
        const int gmBase = bm + wm + i * 16 + (lane >> 4) * 4;
#pragma unroll
        for (int j = 0; j < 4; j++) {
            const int dd = (wn & 63) + j * 16 + (lane & 15);
#pragma unroll
            for (int r = 0; r < 4; r++) {
                const int gm = gmBase + r;
                float val = acc[i][j][r] + bv[j];
                if (t < 2) val *= inv_n[i][r];
                const int b  = gm >> 11;
                const int ii = gm & 2047;
                const size_t dst = (((size_t)(b * 16 + h) * 2048) + ii) * 64 + dd;
                dstbase[dst] = (__bf16)val;
            }
        }
    }
}

// Out projection: C = A(Wh+Wl)^T + bias, A bf16 (2-term), fp32 out.
// TM=128, TN=64 -> 512 blocks (2/CU). Wave owns 64x32.
__global__ __launch_bounds__(256) void gemm_out(
    const __bf16* __restrict__ A,
    const __bf16* __restrict__ Wh, const __bf16* __restrict__ Wl,
    const float* __restrict__ bias, float* __restrict__ C,
    int M, int N, int K)
{
    __shared__ __bf16 sA[TM * BK];
    __shared__ __bf16 sWh[64 * BK];
    __shared__ __bf16 sWl[64 * BK];

    const int tid  = threadIdx.x;
    const int lane = tid & 63;
    const int wave = tid >> 6;
    const int bm = blockIdx.y * TM;
    const int bn = blockIdx.x * 64;
    const int wm = (wave >> 1) * 64;
    const int wn = (wave & 1) * 32;
    const int frow = lane & 15;

    f32x4 acc[4][2] = {};

    for (int k0 = 0; k0 < K; k0 += BK) {
        stage_sw(sA,  A,  bm, K, k0, tid, TM * 8);
        stage_sw(sWh, Wh, bn, K, k0, tid, 64 * 8);
        stage_sw(sWl, Wl, bn, K, k0, tid, 64 * 8);
        __syncthreads();

#pragma unroll
        for (int half = 0; half < 2; half++) {
            const int cf = half * 4 + (lane >> 4);
            bf16x8 aH[4], bH[2], bL[2];
#pragma unroll
            for (int t = 0; t < 4; t++)
                aH[t] = frag_sw(sA, wm + t * 16 + frow, cf);
#pragma unroll
            for (int t = 0; t < 2; t++) {
                bH[t] = frag_sw(sWh, wn + t * 16 + frow, cf);
                bL[t] = frag_sw(sWl, wn + t * 16 + frow, cf);
            }
#pragma unroll
            for (int i = 0; i < 4; i++)
#pragma unroll
                for (int j = 0; j < 2; j++) {
                    acc[i][j] = __builtin_amdgcn_mfma_f32_16x16x32_bf16(aH[i], bH[j], acc[i][j], 0, 0, 0);
                    acc[i][j] = __builtin_amdgcn_mfma_f32_16x16x32_bf16(aH[i], bL[j], acc[i][j], 0, 0, 0);
                }
        }
        __syncthreads();
    }

#pragma unroll
    for (int i = 0; i < 4; i++) {
        const int gmBase = bm + wm + i * 16 + (lane >> 4) * 4;
#pragma unroll
        for (int j = 0; j < 2; j++) {
            const int gn = bn + wn + j * 16 + (lane & 15);
            const float bvj = bias[gn];
#pragma unroll
            for (int r = 0; r < 4; r++)
                C[(size_t)(gmBase + r) * N + gn] = acc[i][j][r] + bvj;
        }
    }
}

// Dilated attention: 4 rows per wave; lane group g=lane>>4 owns row i0+g,
// lane&15 owns 4 head-dims (bf16x4). q,k,v: [B,H,N,64] bf16 (q,k normalized).
__global__ __launch_bounds__(256) void attn_sparse(
    const __bf16* __restrict__ q, const __bf16* __restrict__ k,
    const __bf16* __restrict__ v, __bf16* __restrict__ ao /*[B,N,D] bf16*/)
{
    const int wid  = blockIdx.x * 4 + (threadIdx.x >> 6);
    const int lane = threadIdx.x & 63;
    const int g    = lane >> 4;
    const int ld   = (lane & 15) * 4;

    const int bh = wid >> 9;            // 512 wave-tasks per (b,h)
    const int i  = (wid & 511) * 4 + g; // this lane-group's row

    const __bf16* qb = q + (size_t)bh * 2048 * 64;
    const __bf16* kb = k + (size_t)bh * 2048 * 64;
    const __bf16* vb = v + (size_t)bh * 2048 * 64;

    bf16x4 qv = *(const bf16x4*)(qb + (size_t)i * 64 + ld);
    float q0 = (float)qv[0], q1 = (float)qv[1], q2 = (float)qv[2], q3 = (float)qv[3];

    float s[17];
#pragma unroll
    for (int t = 0; t < 17; t++) {
        const int j = i + 2 * t - 16;
        const bool valid = (j >= 0) && (j < 2048);
        const int jc = valid ? j : i;
        bf16x4 kv = *(const bf16x4*)(kb + (size_t)jc * 64 + ld);
        float prod = q0 * (float)kv[0];
        prod = fmaf(q1, (float)kv[1], prod);
        prod = fmaf(q2, (float)kv[2], prod);
        prod = fmaf(q3, (float)kv[3], prod);
        prod += __shfl_xor(prod, 1);
        prod += __shfl_xor(prod, 2);
        prod += __shfl_xor(prod, 4);
        prod += __shfl_xor(prod, 8);
        s[t] = valid ? prod : -INFINITY;
    }

    float m = s[0];
#pragma unroll
    for (int t = 1; t < 17; t++) m = fmaxf(m, s[t]);
    float denom = 0.f, p[17];
#pragma unroll
    for (int t = 0; t < 17; t++) { p[t] = __expf(s[t] - m); denom += p[t]; }
    const float inv = 1.0f / denom;

    float a0 = 0.f, a1 = 0.f, a2 = 0.f, a3 = 0.f;
#pragma unroll
    for (int t = 0; t < 17; t++) {
        const int j = i + 2 * t - 16;
        const int jc = (j >= 0 && j < 2048) ? j : i;   // p[t]==0 when invalid
        bf16x4 vv = *(const bf16x4*)(vb + (size_t)jc * 64 + ld);
        a0 = fmaf(p[t], (float)vv[0], a0);
        a1 = fmaf(p[t], (float)vv[1], a1);
        a2 = fmaf(p[t], (float)vv[2], a2);
        a3 = fmaf(p[t], (float)vv[3], a3);
    }

    const int b = bh >> 4, h = bh & 15;
    bf16x4 o;
    o[0] = (__bf16)(a0 * inv); o[1] = (__bf16)(a1 * inv);
    o[2] = (__bf16)(a2 * inv); o[3] = (__bf16)(a3 * inv);
    *(bf16x4*)(ao + ((size_t)(b * 2048 + i)) * 1024 + h * 64 + ld) = o;
}

extern "C" void kernel_launch(void* const* d_in, const int* in_sizes, int n_in,
                              void* d_out, int out_size, void* d_ws, size_t ws_size,
                              hipStream_t stream)
{
    const float* x     = (const float*)d_in[0];  // [2,2048,1024]
    const float* w_qkv = (const float*)d_in[1];  // [3072,1024]
    const float* b_qkv = (const float*)d_in[2];  // [3072]
    const float* w_out = (const float*)d_in[3];  // [1024,1024]
    const float* b_out = (const float*)d_in[4];  // [1024]
    float* out = (float*)d_out;                  // [2,2048,1024]

    const int Dn = 1024;
    const int M  = 4096;
    const int nx = 4194304, nwq = 3145728, nwo = 1048576;

    char* p = (char*)d_ws;
    __bf16* q   = (__bf16*)p;  p += (size_t)nx * 2;   // [2,16,2048,64]
    __bf16* kk  = (__bf16*)p;  p += (size_t)nx * 2;
    __bf16* vv  = (__bf16*)p;  p += (size_t)nx * 2;
    __bf16* xh  = (__bf16*)p;  p += (size_t)nx * 2;   // aliased to ao after gemm_qkv
    __bf16* wqh = (__bf16*)p;  p += (size_t)nwq * 2;
    __bf16* woh = (__bf16*)p;  p += (size_t)nwo * 2;
    __bf16* wol = (__bf16*)p;  p += (size_t)nwo * 2;
    __bf16* ao  = xh;

    // 0) x, w_qkv -> bf16 cast; w_out -> hi/lo bf16 split
    {
        dim3 grid(nx / 8 / 256, 3);
        hipLaunchKernelGGL(split_mat, grid, dim3(256), 0, stream,
                           x, xh, (__bf16*)nullptr, nx,
                           w_qkv, wqh, (__bf16*)nullptr, nwq,
                           w_out, woh, wol, nwo);
    }
    // 1) qkv projection (1-term) + fused qk-norm -> q,k,v bf16 head layout
    {
        dim3 grid(3 * Dn / 128, M / TM);
        hipLaunchKernelGGL(gemm_qkv, grid, dim3(256), 0, stream,
                           xh, wqh, b_qkv, q, kk, vv, M, 3 * Dn, Dn);
    }
    // 2) sparse dilated attention -> ao bf16 [B,N,D]
    hipLaunchKernelGGL(attn_sparse, dim3(65536 / 16), dim3(256), 0, stream,
                       q, kk, vv, ao);
    // 3) output projection (2-term) -> fp32 out
    {
        dim3 grid(Dn / 64, M / TM);
        hipLaunchKernelGGL(gemm_out, grid, dim3(256), 0, stream,
                           ao, woh, wol, b_out, out, M, Dn, Dn);
    }
}